// Round 2
// baseline (6415.087 us; speedup 1.0000x reference)
//
#include <hip/hip_runtime.h>

// RGCN 2-layer hetero graph conv. fp32 I/O (per reference dtypes), bf16 MFMA compute
// (2% absmax threshold sanctions bf16 internal precision).
// Pipeline per call:
//   1) warrange_k: rearrange 10 fp32 weight matrices into bf16 MFMA B-fragment layout.
//   2) segmax via order-preserving u32 atomicMax into d_ws (memset-0 == empty == 0-out).
//   3) fused MFMA GEMM per output tensor: root@Wr + b + sum(segmax@Wrel); relu for L1.
// MFMA 16x16x32 bf16 layouts (learn_hip m89 verified):
//   A: row=lane&15, k=(lane>>4)*8+i ; B: col=lane&15, k=(lane>>4)*8+i
//   C/D: col=lane&15, row=(lane>>4)*4+reg

#define DI 128
#define NP 100000
#define NA 50000

typedef short s8v __attribute__((ext_vector_type(8)));
typedef float f32x4 __attribute__((ext_vector_type(4)));

// ---- order-preserving encode/decode: f32 bits <-> monotonic u32 ----
// encode(-inf)=0x007FFFFF; memset-0 init < any real value; decode(u<=0x007FFFFF)=0
__device__ __forceinline__ unsigned int ord_from_bits(unsigned int fb) {
  return fb ^ (unsigned int)(((int)fb >> 31) | (int)0x80000000);
}
__device__ __forceinline__ float f32_from_ord(unsigned int u) {
  unsigned int fb;
  if (u >= 0x80000000u)      fb = u ^ 0x80000000u;
  else if (u <= 0x007FFFFFu) fb = 0u;            // empty segment -> 0
  else                       fb = ~u;
  return __uint_as_float(fb);
}
__device__ __forceinline__ unsigned short bf16_rne(float f) {
  unsigned int fb = __float_as_uint(f);
  fb += 0x7FFFu + ((fb >> 16) & 1u);
  return (unsigned short)(fb >> 16);
}

// ---- scatter-max, fp32 source: per edge, 32 threads x 4 feats ----
__global__ __launch_bounds__(256) void scatter_max_f32(
    const int* __restrict__ src, const int* __restrict__ dst,
    const float* __restrict__ X, unsigned int* __restrict__ S, int E)
{
  int gt = blockIdx.x * 256 + threadIdx.x;
  int e = gt >> 5;
  if (e >= E) return;
  int f4 = (gt & 31) * 4;
  int s = src[e], d = dst[e];
  float4 x = *reinterpret_cast<const float4*>(X + (size_t)s * DI + f4);
  unsigned int* o = S + (size_t)d * DI + f4;
  atomicMax(o + 0, ord_from_bits(__float_as_uint(x.x)));
  atomicMax(o + 1, ord_from_bits(__float_as_uint(x.y)));
  atomicMax(o + 2, ord_from_bits(__float_as_uint(x.z)));
  atomicMax(o + 3, ord_from_bits(__float_as_uint(x.w)));
}

// ---- scatter-max, bf16 source (layer-2 hidden states) ----
__global__ __launch_bounds__(256) void scatter_max_bf16(
    const int* __restrict__ src, const int* __restrict__ dst,
    const unsigned short* __restrict__ X, unsigned int* __restrict__ S, int E)
{
  int gt = blockIdx.x * 256 + threadIdx.x;
  int e = gt >> 5;
  if (e >= E) return;
  int f4 = (gt & 31) * 4;
  int s = src[e], d = dst[e];
  ushort4 x = *reinterpret_cast<const ushort4*>(X + (size_t)s * DI + f4);
  unsigned int* o = S + (size_t)d * DI + f4;
  atomicMax(o + 0, ord_from_bits(((unsigned int)x.x) << 16));
  atomicMax(o + 1, ord_from_bits(((unsigned int)x.y) << 16));
  atomicMax(o + 2, ord_from_bits(((unsigned int)x.z) << 16));
  atomicMax(o + 3, ord_from_bits(((unsigned int)x.w) << 16));
}

// ---- weight rearrange (fp32 -> bf16 B-fragments): wf[((kc*CF+cf)*64+lane)*8+i]=W[k][c] ----
struct WArgs {
  const float* w[10];
  unsigned short* wf[10];
};
__global__ __launch_bounds__(256) void warrange_k(WArgs args) {
  int widx = blockIdx.y;
  int OUTi = (widx < 5) ? 128 : 64;
  int CF = OUTi / 16;
  int nt = 4 * CF * 64;
  int t = blockIdx.x * 256 + threadIdx.x;
  if (t >= nt) return;
  int lane = t & 63, tmp = t >> 6;
  int cf = tmp % CF, kc = tmp / CF;
  int k0 = kc * 32 + (lane >> 4) * 8;
  int c  = cf * 16 + (lane & 15);
  const float* w = args.w[widx];
  s8v v;
  #pragma unroll
  for (int i = 0; i < 8; ++i) v[i] = (short)bf16_rne(w[(k0 + i) * OUTi + c]);
  *(reinterpret_cast<s8v*>(args.wf[widx]) + t) = v;
}

// ---- fused GEMM: out = relu?(A0@W0 + b + S1@W1 [+ S2@W2]) ----
template<int OUT, bool RELU, int NSRC, bool A_BF16, bool OUT_BF16>
__global__ __launch_bounds__(256) void fused_gemm_k(
    const void* __restrict__ A0v, const unsigned short* __restrict__ W0,
    const unsigned int*  __restrict__ S1, const unsigned short* __restrict__ W1,
    const unsigned int*  __restrict__ S2, const unsigned short* __restrict__ W2,
    const float* __restrict__ bias, void* __restrict__ outv, int N)
{
  constexpr int CF = OUT / 16;
  const int lane = threadIdx.x & 63;
  const int wave = threadIdx.x >> 6;
  const int row0 = blockIdx.x * 64 + wave * 16;
  if (row0 >= N) return;
  const int rl = lane & 15, half = lane >> 4;
  const size_t arow = (size_t)(row0 + rl);

  f32x4 acc[CF];
  #pragma unroll
  for (int i = 0; i < CF; ++i) acc[i] = f32x4{0.f, 0.f, 0.f, 0.f};

  // source 0: node features (fp32 or bf16)
  {
    const s8v* w = reinterpret_cast<const s8v*>(W0) + lane;
    #pragma unroll
    for (int kc = 0; kc < 4; ++kc) {
      s8v av;
      if (A_BF16) {
        const unsigned short* a = (const unsigned short*)A0v + arow * DI + half * 8 + kc * 32;
        av = *reinterpret_cast<const s8v*>(a);
      } else {
        const float* a = (const float*)A0v + arow * DI + half * 8 + kc * 32;
        float4 f0 = *reinterpret_cast<const float4*>(a);
        float4 f1 = *reinterpret_cast<const float4*>(a + 4);
        av[0] = (short)bf16_rne(f0.x); av[1] = (short)bf16_rne(f0.y);
        av[2] = (short)bf16_rne(f0.z); av[3] = (short)bf16_rne(f0.w);
        av[4] = (short)bf16_rne(f1.x); av[5] = (short)bf16_rne(f1.y);
        av[6] = (short)bf16_rne(f1.z); av[7] = (short)bf16_rne(f1.w);
      }
      #pragma unroll
      for (int cf = 0; cf < CF; ++cf) {
        s8v wv = w[(kc * CF + cf) * 64];
        acc[cf] = __builtin_amdgcn_mfma_f32_16x16x32_bf16(av, wv, acc[cf], 0, 0, 0);
      }
    }
  }
  // sources 1,2: ordered-u32 segmax buffers
  #pragma unroll
  for (int si = 1; si < NSRC; ++si) {
    const unsigned int* S = (si == 1) ? S1 : S2;
    const unsigned short* W = (si == 1) ? W1 : W2;
    const unsigned int* sp = S + arow * DI + half * 8;
    const s8v* w = reinterpret_cast<const s8v*>(W) + lane;
    #pragma unroll
    for (int kc = 0; kc < 4; ++kc) {
      uint4 u0 = *reinterpret_cast<const uint4*>(sp + kc * 32);
      uint4 u1 = *reinterpret_cast<const uint4*>(sp + kc * 32 + 4);
      s8v av;
      av[0] = (short)bf16_rne(f32_from_ord(u0.x)); av[1] = (short)bf16_rne(f32_from_ord(u0.y));
      av[2] = (short)bf16_rne(f32_from_ord(u0.z)); av[3] = (short)bf16_rne(f32_from_ord(u0.w));
      av[4] = (short)bf16_rne(f32_from_ord(u1.x)); av[5] = (short)bf16_rne(f32_from_ord(u1.y));
      av[6] = (short)bf16_rne(f32_from_ord(u1.z)); av[7] = (short)bf16_rne(f32_from_ord(u1.w));
      #pragma unroll
      for (int cf = 0; cf < CF; ++cf) {
        s8v wv = w[(kc * CF + cf) * 64];
        acc[cf] = __builtin_amdgcn_mfma_f32_16x16x32_bf16(av, wv, acc[cf], 0, 0, 0);
      }
    }
  }

  // epilogue: fp32 bias, relu, store (bf16 for hidden, fp32 for final)
  #pragma unroll
  for (int cf = 0; cf < CF; ++cf) {
    float bv = bias[cf * 16 + rl];
    #pragma unroll
    for (int j = 0; j < 4; ++j) {
      float v = acc[cf][j] + bv;
      if (RELU) v = v > 0.f ? v : 0.f;
      size_t idx = (size_t)(row0 + half * 4 + j) * OUT + cf * 16 + rl;
      if (OUT_BF16) ((unsigned short*)outv)[idx] = bf16_rne(v);
      else          ((float*)outv)[idx] = v;
    }
  }
}

extern "C" void kernel_launch(void* const* d_in, const int* in_sizes, int n_in,
                              void* d_out, int out_size, void* d_ws, size_t ws_size,
                              hipStream_t stream) {
  const float* xp = (const float*)d_in[0];
  const float* xa = (const float*)d_in[1];
  const int* wsrc = (const int*)d_in[2];
  const int* wdst = (const int*)d_in[3];
  const int* csrc = (const int*)d_in[4];
  const int* cdst = (const int*)d_in[5];
  const int* bsrc = (const int*)d_in[6];
  const int* bdst = (const int*)d_in[7];
  const int Ew = in_sizes[2], Ec = in_sizes[4], Eb = in_sizes[6];

  const float* w1w  = (const float*)d_in[8];
  const float* w1c  = (const float*)d_in[9];
  const float* w1wb = (const float*)d_in[10];
  const float* w1rp = (const float*)d_in[11];
  const float* b1rp = (const float*)d_in[12];
  const float* w1ra = (const float*)d_in[13];
  const float* b1ra = (const float*)d_in[14];
  const float* w2w  = (const float*)d_in[15];
  const float* w2c  = (const float*)d_in[16];
  const float* w2wb = (const float*)d_in[17];
  const float* w2rp = (const float*)d_in[18];
  const float* b2rp = (const float*)d_in[19];
  const float* w2ra = (const float*)d_in[20];
  const float* b2ra = (const float*)d_in[21];

  // workspace layout (bytes)
  char* ws = (char*)d_ws;
  unsigned int* S_w  = (unsigned int*)(ws + 0);           // 100000*128*4 = 51.2MB
  unsigned int* S_c  = (unsigned int*)(ws + 51200000);    // 51.2MB
  unsigned int* S_b  = (unsigned int*)(ws + 102400000);   // 50000*128*4 = 25.6MB
  unsigned short* hp = (unsigned short*)(ws + 128000000); // bf16 hidden paper, 25.6MB
  unsigned short* ha = (unsigned short*)(ws + 153600000); // bf16 hidden author, 12.8MB
  unsigned short* wf = (unsigned short*)(ws + 166400000); // bf16 weight fragments, 240KB

  unsigned short* WF[10];
  size_t off = 0;
  for (int i = 0; i < 10; ++i) {
    WF[i] = wf + off;
    off += (i < 5) ? (size_t)128 * 128 : (size_t)128 * 64;
  }
  WArgs wa;
  const float* wsrcs[10] = {w1w, w1c, w1wb, w1rp, w1ra, w2w, w2c, w2wb, w2rp, w2ra};
  for (int i = 0; i < 10; ++i) { wa.w[i] = wsrcs[i]; wa.wf[i] = WF[i]; }

  float* outP = (float*)d_out;                 // 100000 x 64 fp32
  float* outA = outP + (size_t)NP * 64;        // 50000 x 64 fp32

  const int gw = (Ew * 32 + 255) / 256;
  const int gc = (Ec * 32 + 255) / 256;
  const int gb = (Eb * 32 + 255) / 256;
  const int gP = (NP + 63) / 64, gA = (NA + 63) / 64;

  warrange_k<<<dim3(8, 10), 256, 0, stream>>>(wa);

  // ---- layer 1 (fp32 sources) ----
  hipMemsetAsync(ws, 0, 128000000, stream);
  scatter_max_f32<<<gw, 256, 0, stream>>>(wsrc, wdst, xa, S_w, Ew);
  scatter_max_f32<<<gc, 256, 0, stream>>>(csrc, cdst, xp, S_c, Ec);
  scatter_max_f32<<<gb, 256, 0, stream>>>(bsrc, bdst, xp, S_b, Eb);
  fused_gemm_k<128, true, 3, false, true><<<gP, 256, 0, stream>>>(
      xp, WF[3], S_w, WF[0], S_c, WF[1], b1rp, hp, NP);
  fused_gemm_k<128, true, 2, false, true><<<gA, 256, 0, stream>>>(
      xa, WF[4], S_b, WF[2], nullptr, nullptr, b1ra, ha, NA);

  // ---- layer 2 (bf16 hidden sources, fp32 output) ----
  hipMemsetAsync(ws, 0, 128000000, stream);
  scatter_max_bf16<<<gw, 256, 0, stream>>>(wsrc, wdst, ha, S_w, Ew);
  scatter_max_bf16<<<gc, 256, 0, stream>>>(csrc, cdst, hp, S_c, Ec);
  scatter_max_bf16<<<gb, 256, 0, stream>>>(bsrc, bdst, hp, S_b, Eb);
  fused_gemm_k<64, false, 3, true, false><<<gP, 256, 0, stream>>>(
      hp, WF[8], S_w, WF[5], S_c, WF[6], b2rp, outP, NP);
  fused_gemm_k<64, false, 2, true, false><<<gA, 256, 0, stream>>>(
      ha, WF[9], S_b, WF[7], nullptr, nullptr, b2ra, outA, NA);
}

// Round 3
// 779.575 us; speedup vs baseline: 8.2290x; 8.2290x over previous
//
#include <hip/hip_runtime.h>

// RGCN 2-layer hetero graph conv. fp32 I/O, bf16 MFMA compute.
// R3: replace atomic scatter-max (6 x 1052us, atomic-throughput-bound) with
// per-call CSR bucketing + register gather-max. Edge structure is shared by
// both layers, so CSR is built once (3 edge types) and used by 6 gathers.
// Features are bf16-ified up front (RNE monotonic => max commutes with round).

#define DI 128
#define NP 100000
#define NA 50000

typedef short s8v __attribute__((ext_vector_type(8)));
typedef float f32x4 __attribute__((ext_vector_type(4)));

__device__ __forceinline__ unsigned short bf16_rne(float f) {
  unsigned int fb = __float_as_uint(f);
  fb += 0x7FFFu + ((fb >> 16) & 1u);
  return (unsigned short)(fb >> 16);
}

// ---- fp32 -> bf16, 4 elems/thread ----
__global__ __launch_bounds__(256) void cvt_bf16_k(const float* __restrict__ X,
                                                  unsigned short* __restrict__ Y, int n4) {
  int i = blockIdx.x * 256 + threadIdx.x;
  if (i >= n4) return;
  float4 f = reinterpret_cast<const float4*>(X)[i];
  ushort4 o;
  o.x = bf16_rne(f.x); o.y = bf16_rne(f.y); o.z = bf16_rne(f.z); o.w = bf16_rne(f.w);
  reinterpret_cast<ushort4*>(Y)[i] = o;
}

// ---- CSR build: histogram -> scan -> fill ----
__global__ __launch_bounds__(256) void hist_k(const int* __restrict__ dst,
                                              int* __restrict__ cnt, int E) {
  int e = blockIdx.x * 256 + threadIdx.x;
  if (e < E) atomicAdd(&cnt[dst[e]], 1);
}

// block = 256 thr x 4 elems = 1024; bsum[b] = sum of chunk
__global__ __launch_bounds__(256) void scan_blocksum_k(const int* __restrict__ cnt,
                                                       int* __restrict__ bsum, int n) {
  __shared__ int red[256];
  int t = threadIdx.x;
  int base = blockIdx.x * 1024 + t * 4;
  int s = 0;
  #pragma unroll
  for (int i = 0; i < 4; ++i) { int idx = base + i; if (idx < n) s += cnt[idx]; }
  red[t] = s; __syncthreads();
  #pragma unroll
  for (int o = 128; o > 0; o >>= 1) { if (t < o) red[t] += red[t + o]; __syncthreads(); }
  if (t == 0) bsum[blockIdx.x] = red[0];
}

__global__ void scan_partials_k(int* bsum, int nb) {
  if (threadIdx.x == 0 && blockIdx.x == 0) {
    int acc = 0;
    for (int i = 0; i < nb; ++i) { int v = bsum[i]; bsum[i] = acc; acc += v; }
  }
}

__global__ __launch_bounds__(256) void scan_write_k(const int* __restrict__ cnt,
                                                    const int* __restrict__ bsum,
                                                    int* __restrict__ rs, int n) {
  __shared__ int ts[256];
  int t = threadIdx.x;
  int base = blockIdx.x * 1024 + t * 4;
  int v[4]; int s = 0;
  #pragma unroll
  for (int i = 0; i < 4; ++i) { int idx = base + i; v[i] = (idx < n) ? cnt[idx] : 0; s += v[i]; }
  ts[t] = s; __syncthreads();
  int inc = s;
  for (int o = 1; o < 256; o <<= 1) {
    int y = (t >= o) ? ts[t - o] : 0;
    __syncthreads();
    inc += y; ts[t] = inc;
    __syncthreads();
  }
  int p = bsum[blockIdx.x] + inc - s;  // exclusive prefix for this thread's 4-chunk
  #pragma unroll
  for (int i = 0; i < 4; ++i) { int idx = base + i; if (idx < n) { rs[idx] = p; p += v[i]; } }
}

__global__ __launch_bounds__(256) void fill_k(const int* __restrict__ src,
                                              const int* __restrict__ dst,
                                              const int* __restrict__ rs,
                                              int* __restrict__ cursor,
                                              int* __restrict__ bkt, int E) {
  int e = blockIdx.x * 256 + threadIdx.x;
  if (e >= E) return;
  int d = dst[e];
  int pos = atomicAdd(&cursor[d], 1);
  bkt[rs[d] + pos] = src[e];
}

// ---- gather-max: one wave per dst row; lane owns 2 features (4B) ----
__global__ __launch_bounds__(256) void gather_max_k(
    const int* __restrict__ cnt, const int* __restrict__ rs,
    const int* __restrict__ bkt, const unsigned short* __restrict__ Xb,
    unsigned short* __restrict__ S, int N)
{
  int lane = threadIdx.x & 63;
  int d = blockIdx.x * 4 + (threadIdx.x >> 6);
  if (d >= N) return;
  int deg = cnt[d], base = rs[d];
  unsigned int out;
  if (deg == 0) {
    out = 0u;  // torch_sparse convention: empty segment -> 0
  } else {
    float m0 = -3.4e38f, m1 = -3.4e38f;
    int s = bkt[base];
    for (int e = 0; e < deg; ++e) {
      int nn = (e + 1 < deg) ? bkt[base + e + 1] : s;  // prefetch next index
      unsigned int u = *reinterpret_cast<const unsigned int*>(Xb + (size_t)s * DI + lane * 2);
      m0 = fmaxf(m0, __uint_as_float(u << 16));
      m1 = fmaxf(m1, __uint_as_float(u & 0xFFFF0000u));
      s = nn;
    }
    out = (__float_as_uint(m0) >> 16) | (__float_as_uint(m1) & 0xFFFF0000u);
  }
  *reinterpret_cast<unsigned int*>(S + (size_t)d * DI + lane * 2) = out;
}

// ---- weight rearrange (fp32 -> bf16 B-fragments): wf[((kc*CF+cf)*64+lane)*8+i]=W[k][c] ----
struct WArgs {
  const float* w[10];
  unsigned short* wf[10];
};
__global__ __launch_bounds__(256) void warrange_k(WArgs args) {
  int widx = blockIdx.y;
  int OUTi = (widx < 5) ? 128 : 64;
  int CF = OUTi / 16;
  int nt = 4 * CF * 64;
  int t = blockIdx.x * 256 + threadIdx.x;
  if (t >= nt) return;
  int lane = t & 63, tmp = t >> 6;
  int cf = tmp % CF, kc = tmp / CF;
  int k0 = kc * 32 + (lane >> 4) * 8;
  int c  = cf * 16 + (lane & 15);
  const float* w = args.w[widx];
  s8v v;
  #pragma unroll
  for (int i = 0; i < 8; ++i) v[i] = (short)bf16_rne(w[(k0 + i) * OUTi + c]);
  *(reinterpret_cast<s8v*>(args.wf[widx]) + t) = v;
}

// ---- fused GEMM: out = relu?(A0@W0 + b + A1@W1 [+ A2@W2]), all A bf16 ----
// MFMA 16x16x32 bf16: A row=lane&15,k=(lane>>4)*8+i; B col=lane&15; D col=lane&15,row=(lane>>4)*4+reg
template<int OUT, bool RELU, int NSRC, bool OUT_BF16>
__global__ __launch_bounds__(256) void fused_gemm_k(
    const unsigned short* __restrict__ A0, const unsigned short* __restrict__ W0,
    const unsigned short* __restrict__ A1, const unsigned short* __restrict__ W1,
    const unsigned short* __restrict__ A2, const unsigned short* __restrict__ W2,
    const float* __restrict__ bias, void* __restrict__ outv, int N)
{
  constexpr int CF = OUT / 16;
  const int lane = threadIdx.x & 63;
  const int wave = threadIdx.x >> 6;
  const int row0 = blockIdx.x * 64 + wave * 16;
  if (row0 >= N) return;
  const int rl = lane & 15, half = lane >> 4;
  const size_t arow = (size_t)(row0 + rl);

  f32x4 acc[CF];
  #pragma unroll
  for (int i = 0; i < CF; ++i) acc[i] = f32x4{0.f, 0.f, 0.f, 0.f};

  const unsigned short* As[3] = {A0, A1, A2};
  const unsigned short* Ws[3] = {W0, W1, W2};
  #pragma unroll
  for (int si = 0; si < NSRC; ++si) {
    const s8v* a = reinterpret_cast<const s8v*>(As[si] + arow * DI + half * 8);
    const s8v* w = reinterpret_cast<const s8v*>(Ws[si]) + lane;
    #pragma unroll
    for (int kc = 0; kc < 4; ++kc) {
      s8v av = a[kc * 4];
      #pragma unroll
      for (int cf = 0; cf < CF; ++cf)
        acc[cf] = __builtin_amdgcn_mfma_f32_16x16x32_bf16(av, w[(kc * CF + cf) * 64], acc[cf], 0, 0, 0);
    }
  }

  #pragma unroll
  for (int cf = 0; cf < CF; ++cf) {
    float bv = bias[cf * 16 + rl];
    #pragma unroll
    for (int j = 0; j < 4; ++j) {
      int r = row0 + half * 4 + j;
      if (r >= N) continue;  // tail guard
      float v = acc[cf][j] + bv;
      if (RELU) v = v > 0.f ? v : 0.f;
      size_t idx = (size_t)r * OUT + cf * 16 + rl;
      if (OUT_BF16) ((unsigned short*)outv)[idx] = bf16_rne(v);
      else          ((float*)outv)[idx] = v;
    }
  }
}

extern "C" void kernel_launch(void* const* d_in, const int* in_sizes, int n_in,
                              void* d_out, int out_size, void* d_ws, size_t ws_size,
                              hipStream_t stream) {
  const float* xp = (const float*)d_in[0];
  const float* xa = (const float*)d_in[1];
  const int* wsrc = (const int*)d_in[2];
  const int* wdst = (const int*)d_in[3];
  const int* csrc = (const int*)d_in[4];
  const int* cdst = (const int*)d_in[5];
  const int* bsrc = (const int*)d_in[6];
  const int* bdst = (const int*)d_in[7];
  const int Ew = in_sizes[2], Ec = in_sizes[4], Eb = in_sizes[6];

  const float* w1w  = (const float*)d_in[8];
  const float* w1c  = (const float*)d_in[9];
  const float* w1wb = (const float*)d_in[10];
  const float* w1rp = (const float*)d_in[11];
  const float* b1rp = (const float*)d_in[12];
  const float* w1ra = (const float*)d_in[13];
  const float* b1ra = (const float*)d_in[14];
  const float* w2w  = (const float*)d_in[15];
  const float* w2c  = (const float*)d_in[16];
  const float* w2wb = (const float*)d_in[17];
  const float* w2rp = (const float*)d_in[18];
  const float* b2rp = (const float*)d_in[19];
  const float* w2ra = (const float*)d_in[20];
  const float* b2ra = (const float*)d_in[21];

  // ---- workspace layout (bytes) ----
  char* ws = (char*)d_ws;
  unsigned short* xpb = (unsigned short*)(ws + 0);           // 25,600,000
  unsigned short* xab = (unsigned short*)(ws + 25600000);    // 12,800,000
  unsigned short* hp  = (unsigned short*)(ws + 38400000);    // 25,600,000
  unsigned short* ha  = (unsigned short*)(ws + 64000000);    // 12,800,000
  unsigned short* S_w = (unsigned short*)(ws + 76800000);    // 25,600,000 (paper dst)
  unsigned short* S_c = (unsigned short*)(ws + 102400000);   // 25,600,000 (paper dst)
  unsigned short* S_b = (unsigned short*)(ws + 128000000);   // 12,800,000 (author dst)
  int* bkt_w = (int*)(ws + 140800000);                       // 3,200,000
  int* bkt_c = (int*)(ws + 144000000);                       // 3,200,000
  int* bkt_b = (int*)(ws + 147200000);                       // 3,200,000
  int* cnt_w = (int*)(ws + 150400000);                       // 400,000
  int* cnt_c = (int*)(ws + 150800000);                       // 400,000
  int* cnt_b = (int*)(ws + 151200000);                       // 200,000
  int* cur_w = (int*)(ws + 151400000);                       // 400,000
  int* cur_c = (int*)(ws + 151800000);                       // 400,000
  int* cur_b = (int*)(ws + 152200000);                       // 200,000  (cnt+cur = one 2MB memset)
  int* rs_w  = (int*)(ws + 152400000);                       // 400,000
  int* rs_c  = (int*)(ws + 152800000);                       // 400,000
  int* rs_b  = (int*)(ws + 153200000);                       // 200,000
  int* bsum_w = (int*)(ws + 153400000);                      // 4,096
  int* bsum_c = (int*)(ws + 153404096);                      // 4,096
  int* bsum_b = (int*)(ws + 153408192);                      // 4,096
  unsigned short* wf = (unsigned short*)(ws + 153412288);    // 245,760

  unsigned short* WF[10];
  size_t off = 0;
  for (int i = 0; i < 10; ++i) {
    WF[i] = wf + off;
    off += (i < 5) ? (size_t)128 * 128 : (size_t)128 * 64;
  }
  WArgs wa;
  const float* wsrcs[10] = {w1w, w1c, w1wb, w1rp, w1ra, w2w, w2c, w2wb, w2rp, w2ra};
  for (int i = 0; i < 10; ++i) { wa.w[i] = wsrcs[i]; wa.wf[i] = WF[i]; }

  float* outP = (float*)d_out;              // 100000 x 64 fp32
  float* outA = outP + (size_t)NP * 64;     // 50000 x 64 fp32

  const int gE  = (800000 + 255) / 256;     // Ew==Ec==Eb==800000
  const int nbP = (NP + 1023) / 1024, nbA = (NA + 1023) / 1024;
  const int gP  = (NP + 63) / 64, gA = (NA + 63) / 64;
  const int ggP = (NP + 3) / 4,  ggA = (NA + 3) / 4;

  warrange_k<<<dim3(8, 10), 256, 0, stream>>>(wa);
  cvt_bf16_k<<<(NP * DI / 4 + 255) / 256, 256, 0, stream>>>(xp, xpb, NP * DI / 4);
  cvt_bf16_k<<<(NA * DI / 4 + 255) / 256, 256, 0, stream>>>(xa, xab, NA * DI / 4);

  // ---- CSR build (shared by both layers) ----
  hipMemsetAsync(ws + 150400000, 0, 2000000, stream);  // counts + cursors
  hist_k<<<gE, 256, 0, stream>>>(wdst, cnt_w, Ew);
  hist_k<<<gE, 256, 0, stream>>>(cdst, cnt_c, Ec);
  hist_k<<<gE, 256, 0, stream>>>(bdst, cnt_b, Eb);
  scan_blocksum_k<<<nbP, 256, 0, stream>>>(cnt_w, bsum_w, NP);
  scan_blocksum_k<<<nbP, 256, 0, stream>>>(cnt_c, bsum_c, NP);
  scan_blocksum_k<<<nbA, 256, 0, stream>>>(cnt_b, bsum_b, NA);
  scan_partials_k<<<1, 64, 0, stream>>>(bsum_w, nbP);
  scan_partials_k<<<1, 64, 0, stream>>>(bsum_c, nbP);
  scan_partials_k<<<1, 64, 0, stream>>>(bsum_b, nbA);
  scan_write_k<<<nbP, 256, 0, stream>>>(cnt_w, bsum_w, rs_w, NP);
  scan_write_k<<<nbP, 256, 0, stream>>>(cnt_c, bsum_c, rs_c, NP);
  scan_write_k<<<nbA, 256, 0, stream>>>(cnt_b, bsum_b, rs_b, NA);
  fill_k<<<gE, 256, 0, stream>>>(wsrc, wdst, rs_w, cur_w, bkt_w, Ew);
  fill_k<<<gE, 256, 0, stream>>>(csrc, cdst, rs_c, cur_c, bkt_c, Ec);
  fill_k<<<gE, 256, 0, stream>>>(bsrc, bdst, rs_b, cur_b, bkt_b, Eb);

  // ---- layer 1 ----
  gather_max_k<<<ggP, 256, 0, stream>>>(cnt_w, rs_w, bkt_w, xab, S_w, NP);
  gather_max_k<<<ggP, 256, 0, stream>>>(cnt_c, rs_c, bkt_c, xpb, S_c, NP);
  gather_max_k<<<ggA, 256, 0, stream>>>(cnt_b, rs_b, bkt_b, xpb, S_b, NA);
  fused_gemm_k<128, true, 3, true><<<gP, 256, 0, stream>>>(
      xpb, WF[3], S_w, WF[0], S_c, WF[1], b1rp, hp, NP);
  fused_gemm_k<128, true, 2, true><<<gA, 256, 0, stream>>>(
      xab, WF[4], S_b, WF[2], nullptr, nullptr, b1ra, ha, NA);

  // ---- layer 2 ----
  gather_max_k<<<ggP, 256, 0, stream>>>(cnt_w, rs_w, bkt_w, ha, S_w, NP);
  gather_max_k<<<ggP, 256, 0, stream>>>(cnt_c, rs_c, bkt_c, hp, S_c, NP);
  gather_max_k<<<ggA, 256, 0, stream>>>(cnt_b, rs_b, bkt_b, hp, S_b, NA);
  fused_gemm_k<64, false, 3, false><<<gP, 256, 0, stream>>>(
      hp, WF[8], S_w, WF[5], S_c, WF[6], b2rp, outP, NP);
  fused_gemm_k<64, false, 2, false><<<gA, 256, 0, stream>>>(
      ha, WF[9], S_b, WF[7], nullptr, nullptr, b2ra, outA, NA);
}

// Round 4
// 541.764 us; speedup vs baseline: 11.8411x; 1.4390x over previous
//
#include <hip/hip_runtime.h>

// RGCN 2-layer hetero graph conv. fp32 I/O, bf16 MFMA compute.
// R4: gather-max v2 (16 lanes/row, dwordx4, 4 rows/wave, unroll-2 -> 8 row-streams
// in flight per wave), merged 3-way dispatches (grid.y) for hist/scan/fill/gather,
// parallel block-sum scan (replaces serial single-thread scan).

#define DI 128
#define NP 100000
#define NA 50000

typedef short s8v __attribute__((ext_vector_type(8)));
typedef float f32x4 __attribute__((ext_vector_type(4)));

__device__ __forceinline__ unsigned short bf16_rne(float f) {
  unsigned int fb = __float_as_uint(f);
  fb += 0x7FFFu + ((fb >> 16) & 1u);
  return (unsigned short)(fb >> 16);
}

// ---- fp32 -> bf16, 4 elems/thread ----
__global__ __launch_bounds__(256) void cvt_bf16_k(const float* __restrict__ X,
                                                  unsigned short* __restrict__ Y, int n4) {
  int i = blockIdx.x * 256 + threadIdx.x;
  if (i >= n4) return;
  float4 f = reinterpret_cast<const float4*>(X)[i];
  ushort4 o;
  o.x = bf16_rne(f.x); o.y = bf16_rne(f.y); o.z = bf16_rne(f.z); o.w = bf16_rne(f.w);
  reinterpret_cast<ushort4*>(Y)[i] = o;
}

// ==== CSR build (3 edge types in one dispatch via blockIdx.y) ====
struct E3Args {
  const int* src[3]; const int* dst[3];
  int* cnt[3]; int* cur[3]; const int* rs[3]; int* bkt[3];
  int E[3];
};

__global__ __launch_bounds__(256) void hist3_k(E3Args a) {
  int y = blockIdx.y;
  int e = blockIdx.x * 256 + threadIdx.x;
  if (e < a.E[y]) atomicAdd(&a.cnt[y][a.dst[y][e]], 1);
}

__global__ __launch_bounds__(256) void fill3_k(E3Args a) {
  int y = blockIdx.y;
  int e = blockIdx.x * 256 + threadIdx.x;
  if (e >= a.E[y]) return;
  int d = a.dst[y][e];
  int pos = atomicAdd(&a.cur[y][d], 1);
  a.bkt[y][a.rs[y][d] + pos] = a.src[y][e];
}

struct S3Args {
  const int* cnt[3]; int* bsum[3]; int* rs[3];
  int n[3]; int nb[3];
};

// block = 256 thr x 4 elems = 1024 per block; bsum[y][b] = chunk sum
__global__ __launch_bounds__(256) void blocksum3_k(S3Args a) {
  int y = blockIdx.y;
  int n = a.n[y];
  if (blockIdx.x * 1024 >= n) return;  // uniform whole-block exit
  __shared__ int red[256];
  int t = threadIdx.x;
  int base = blockIdx.x * 1024 + t * 4;
  int s = 0;
  #pragma unroll
  for (int i = 0; i < 4; ++i) { int idx = base + i; if (idx < n) s += a.cnt[y][idx]; }
  red[t] = s; __syncthreads();
  #pragma unroll
  for (int o = 128; o > 0; o >>= 1) { if (t < o) red[t] += red[t + o]; __syncthreads(); }
  if (t == 0) a.bsum[y][blockIdx.x] = red[0];
}

// grid = 3 blocks; parallel exclusive scan of bsum[y][0..nb) (nb <= 256)
__global__ __launch_bounds__(256) void partials3_k(S3Args a) {
  __shared__ int sm[256];
  int y = blockIdx.x;
  int nb = a.nb[y];
  int t = threadIdx.x;
  int v = (t < nb) ? a.bsum[y][t] : 0;
  sm[t] = v; __syncthreads();
  int acc = v;
  for (int o = 1; o < 256; o <<= 1) {
    int u = (t >= o) ? sm[t - o] : 0;
    __syncthreads();
    acc += u; sm[t] = acc;
    __syncthreads();
  }
  if (t < nb) a.bsum[y][t] = acc - v;  // exclusive
}

__global__ __launch_bounds__(256) void scanwrite3_k(S3Args a) {
  int y = blockIdx.y;
  int n = a.n[y];
  if (blockIdx.x * 1024 >= n) return;  // uniform whole-block exit
  __shared__ int ts[256];
  int t = threadIdx.x;
  int base = blockIdx.x * 1024 + t * 4;
  int v[4]; int s = 0;
  #pragma unroll
  for (int i = 0; i < 4; ++i) { int idx = base + i; v[i] = (idx < n) ? a.cnt[y][idx] : 0; s += v[i]; }
  ts[t] = s; __syncthreads();
  int inc = s;
  for (int o = 1; o < 256; o <<= 1) {
    int u = (t >= o) ? ts[t - o] : 0;
    __syncthreads();
    inc += u; ts[t] = inc;
    __syncthreads();
  }
  int p = a.bsum[y][blockIdx.x] + inc - s;
  #pragma unroll
  for (int i = 0; i < 4; ++i) { int idx = base + i; if (idx < n) { a.rs[y][idx] = p; p += v[i]; } }
}

// ==== gather-max v2: 16 lanes/row (dwordx4), 4 rows/wave, 16 rows/block, 3-way y ====
struct G3Args {
  const int* cnt[3]; const int* rs[3]; const int* bkt[3];
  const unsigned short* X[3]; unsigned short* S[3];
  int N[3];
};

__global__ __launch_bounds__(256) void gather3_k(G3Args a) {
  const int y = blockIdx.y;
  const int lane = threadIdx.x & 63;
  const int wave = threadIdx.x >> 6;
  const int g = lane >> 4, lg = lane & 15;
  const int d = blockIdx.x * 16 + wave * 4 + g;
  if (d >= a.N[y]) return;

  unsigned short* So = a.S[y] + (size_t)d * DI + lg * 8;
  const int deg = a.cnt[y][d];
  if (deg == 0) {
    uint4 z; z.x = z.y = z.z = z.w = 0u;
    *reinterpret_cast<uint4*>(So) = z;
    return;
  }
  const int* bp = a.bkt[y] + a.rs[y][d];
  const unsigned short* X = a.X[y];

  float ml[4], mh[4];
  #pragma unroll
  for (int j = 0; j < 4; ++j) { ml[j] = -3.4e38f; mh[j] = -3.4e38f; }

  int s0 = bp[0];
  for (int e = 0; e < deg; e += 2) {
    int s1 = (e + 1 < deg) ? bp[e + 1] : s0;  // branchless tail: re-max same row
    int sn = (e + 2 < deg) ? bp[e + 2] : s0;
    uint4 r0 = *reinterpret_cast<const uint4*>(X + (size_t)s0 * DI + lg * 8);
    uint4 r1 = *reinterpret_cast<const uint4*>(X + (size_t)s1 * DI + lg * 8);
    unsigned int w0[4] = {r0.x, r0.y, r0.z, r0.w};
    unsigned int w1[4] = {r1.x, r1.y, r1.z, r1.w};
    #pragma unroll
    for (int j = 0; j < 4; ++j) {
      ml[j] = fmaxf(ml[j], __uint_as_float(w0[j] << 16));
      mh[j] = fmaxf(mh[j], __uint_as_float(w0[j] & 0xFFFF0000u));
      ml[j] = fmaxf(ml[j], __uint_as_float(w1[j] << 16));
      mh[j] = fmaxf(mh[j], __uint_as_float(w1[j] & 0xFFFF0000u));
    }
    s0 = sn;
  }
  uint4 o;
  o.x = (__float_as_uint(ml[0]) >> 16) | (__float_as_uint(mh[0]) & 0xFFFF0000u);
  o.y = (__float_as_uint(ml[1]) >> 16) | (__float_as_uint(mh[1]) & 0xFFFF0000u);
  o.z = (__float_as_uint(ml[2]) >> 16) | (__float_as_uint(mh[2]) & 0xFFFF0000u);
  o.w = (__float_as_uint(ml[3]) >> 16) | (__float_as_uint(mh[3]) & 0xFFFF0000u);
  *reinterpret_cast<uint4*>(So) = o;
}

// ---- weight rearrange (fp32 -> bf16 B-fragments): wf[((kc*CF+cf)*64+lane)*8+i]=W[k][c] ----
struct WArgs {
  const float* w[10];
  unsigned short* wf[10];
};
__global__ __launch_bounds__(256) void warrange_k(WArgs args) {
  int widx = blockIdx.y;
  int OUTi = (widx < 5) ? 128 : 64;
  int CF = OUTi / 16;
  int nt = 4 * CF * 64;
  int t = blockIdx.x * 256 + threadIdx.x;
  if (t >= nt) return;
  int lane = t & 63, tmp = t >> 6;
  int cf = tmp % CF, kc = tmp / CF;
  int k0 = kc * 32 + (lane >> 4) * 8;
  int c  = cf * 16 + (lane & 15);
  const float* w = args.w[widx];
  s8v v;
  #pragma unroll
  for (int i = 0; i < 8; ++i) v[i] = (short)bf16_rne(w[(k0 + i) * OUTi + c]);
  *(reinterpret_cast<s8v*>(args.wf[widx]) + t) = v;
}

// ---- fused GEMM: out = relu?(A0@W0 + b + A1@W1 [+ A2@W2]), all A bf16 ----
// MFMA 16x16x32 bf16: A row=lane&15,k=(lane>>4)*8+i; B col=lane&15; D col=lane&15,row=(lane>>4)*4+reg
template<int OUT, bool RELU, int NSRC, bool OUT_BF16>
__global__ __launch_bounds__(256) void fused_gemm_k(
    const unsigned short* __restrict__ A0, const unsigned short* __restrict__ W0,
    const unsigned short* __restrict__ A1, const unsigned short* __restrict__ W1,
    const unsigned short* __restrict__ A2, const unsigned short* __restrict__ W2,
    const float* __restrict__ bias, void* __restrict__ outv, int N)
{
  constexpr int CF = OUT / 16;
  const int lane = threadIdx.x & 63;
  const int wave = threadIdx.x >> 6;
  const int row0 = blockIdx.x * 64 + wave * 16;
  if (row0 >= N) return;
  const int rl = lane & 15, half = lane >> 4;
  const size_t arow = (size_t)(row0 + rl);

  f32x4 acc[CF];
  #pragma unroll
  for (int i = 0; i < CF; ++i) acc[i] = f32x4{0.f, 0.f, 0.f, 0.f};

  const unsigned short* As[3] = {A0, A1, A2};
  const unsigned short* Ws[3] = {W0, W1, W2};
  #pragma unroll
  for (int si = 0; si < NSRC; ++si) {
    const s8v* a = reinterpret_cast<const s8v*>(As[si] + arow * DI + half * 8);
    const s8v* w = reinterpret_cast<const s8v*>(Ws[si]) + lane;
    #pragma unroll
    for (int kc = 0; kc < 4; ++kc) {
      s8v av = a[kc * 4];
      #pragma unroll
      for (int cf = 0; cf < CF; ++cf)
        acc[cf] = __builtin_amdgcn_mfma_f32_16x16x32_bf16(av, w[(kc * CF + cf) * 64], acc[cf], 0, 0, 0);
    }
  }

  #pragma unroll
  for (int cf = 0; cf < CF; ++cf) {
    float bv = bias[cf * 16 + rl];
    #pragma unroll
    for (int j = 0; j < 4; ++j) {
      int r = row0 + half * 4 + j;
      if (r >= N) continue;
      float v = acc[cf][j] + bv;
      if (RELU) v = v > 0.f ? v : 0.f;
      size_t idx = (size_t)r * OUT + cf * 16 + rl;
      if (OUT_BF16) ((unsigned short*)outv)[idx] = bf16_rne(v);
      else          ((float*)outv)[idx] = v;
    }
  }
}

extern "C" void kernel_launch(void* const* d_in, const int* in_sizes, int n_in,
                              void* d_out, int out_size, void* d_ws, size_t ws_size,
                              hipStream_t stream) {
  const float* xp = (const float*)d_in[0];
  const float* xa = (const float*)d_in[1];
  const int* wsrc = (const int*)d_in[2];
  const int* wdst = (const int*)d_in[3];
  const int* csrc = (const int*)d_in[4];
  const int* cdst = (const int*)d_in[5];
  const int* bsrc = (const int*)d_in[6];
  const int* bdst = (const int*)d_in[7];
  const int Ew = in_sizes[2], Ec = in_sizes[4], Eb = in_sizes[6];

  const float* w1w  = (const float*)d_in[8];
  const float* w1c  = (const float*)d_in[9];
  const float* w1wb = (const float*)d_in[10];
  const float* w1rp = (const float*)d_in[11];
  const float* b1rp = (const float*)d_in[12];
  const float* w1ra = (const float*)d_in[13];
  const float* b1ra = (const float*)d_in[14];
  const float* w2w  = (const float*)d_in[15];
  const float* w2c  = (const float*)d_in[16];
  const float* w2wb = (const float*)d_in[17];
  const float* w2rp = (const float*)d_in[18];
  const float* b2rp = (const float*)d_in[19];
  const float* w2ra = (const float*)d_in[20];
  const float* b2ra = (const float*)d_in[21];

  // ---- workspace layout (bytes) ----
  char* ws = (char*)d_ws;
  unsigned short* xpb = (unsigned short*)(ws + 0);           // 25,600,000
  unsigned short* xab = (unsigned short*)(ws + 25600000);    // 12,800,000
  unsigned short* hp  = (unsigned short*)(ws + 38400000);    // 25,600,000
  unsigned short* ha  = (unsigned short*)(ws + 64000000);    // 12,800,000
  unsigned short* S_w = (unsigned short*)(ws + 76800000);    // 25,600,000
  unsigned short* S_c = (unsigned short*)(ws + 102400000);   // 25,600,000
  unsigned short* S_b = (unsigned short*)(ws + 128000000);   // 12,800,000
  int* bkt_w = (int*)(ws + 140800000);                       // 3,200,000
  int* bkt_c = (int*)(ws + 144000000);                       // 3,200,000
  int* bkt_b = (int*)(ws + 147200000);                       // 3,200,000
  int* cnt_w = (int*)(ws + 150400000);                       // 400,000
  int* cnt_c = (int*)(ws + 150800000);                       // 400,000
  int* cnt_b = (int*)(ws + 151200000);                       // 200,000
  int* cur_w = (int*)(ws + 151400000);                       // 400,000
  int* cur_c = (int*)(ws + 151800000);                       // 400,000
  int* cur_b = (int*)(ws + 152200000);                       // 200,000 (cnt+cur = one 2MB memset)
  int* rs_w  = (int*)(ws + 152400000);                       // 400,000
  int* rs_c  = (int*)(ws + 152800000);                       // 400,000
  int* rs_b  = (int*)(ws + 153200000);                       // 200,000
  int* bsum_w = (int*)(ws + 153400000);                      // 4,096
  int* bsum_c = (int*)(ws + 153404096);                      // 4,096
  int* bsum_b = (int*)(ws + 153408192);                      // 4,096
  unsigned short* wf = (unsigned short*)(ws + 153412288);    // 245,760

  unsigned short* WF[10];
  size_t off = 0;
  for (int i = 0; i < 10; ++i) {
    WF[i] = wf + off;
    off += (i < 5) ? (size_t)128 * 128 : (size_t)128 * 64;
  }
  WArgs wa;
  const float* wsrcs[10] = {w1w, w1c, w1wb, w1rp, w1ra, w2w, w2c, w2wb, w2rp, w2ra};
  for (int i = 0; i < 10; ++i) { wa.w[i] = wsrcs[i]; wa.wf[i] = WF[i]; }

  float* outP = (float*)d_out;              // 100000 x 64 fp32
  float* outA = outP + (size_t)NP * 64;     // 50000 x 64 fp32

  const int gE  = (800000 + 255) / 256;
  const int nbP = (NP + 1023) / 1024, nbA = (NA + 1023) / 1024;  // 98, 49
  const int gP  = (NP + 63) / 64, gA = (NA + 63) / 64;
  const int gG  = (NP + 15) / 16;                                // 6250

  E3Args ea;
  ea.src[0] = wsrc; ea.dst[0] = wdst; ea.cnt[0] = cnt_w; ea.cur[0] = cur_w; ea.rs[0] = rs_w; ea.bkt[0] = bkt_w; ea.E[0] = Ew;
  ea.src[1] = csrc; ea.dst[1] = cdst; ea.cnt[1] = cnt_c; ea.cur[1] = cur_c; ea.rs[1] = rs_c; ea.bkt[1] = bkt_c; ea.E[1] = Ec;
  ea.src[2] = bsrc; ea.dst[2] = bdst; ea.cnt[2] = cnt_b; ea.cur[2] = cur_b; ea.rs[2] = rs_b; ea.bkt[2] = bkt_b; ea.E[2] = Eb;

  S3Args sa;
  sa.cnt[0] = cnt_w; sa.bsum[0] = bsum_w; sa.rs[0] = rs_w; sa.n[0] = NP; sa.nb[0] = nbP;
  sa.cnt[1] = cnt_c; sa.bsum[1] = bsum_c; sa.rs[1] = rs_c; sa.n[1] = NP; sa.nb[1] = nbP;
  sa.cnt[2] = cnt_b; sa.bsum[2] = bsum_b; sa.rs[2] = rs_b; sa.n[2] = NA; sa.nb[2] = nbA;

  G3Args g1, g2;
  for (int i = 0; i < 3; ++i) {
    g1.cnt[i] = g2.cnt[i] = (i == 0) ? cnt_w : (i == 1) ? cnt_c : cnt_b;
    g1.rs[i]  = g2.rs[i]  = (i == 0) ? rs_w  : (i == 1) ? rs_c  : rs_b;
    g1.bkt[i] = g2.bkt[i] = (i == 0) ? bkt_w : (i == 1) ? bkt_c : bkt_b;
    g1.S[i]   = g2.S[i]   = (i == 0) ? S_w   : (i == 1) ? S_c   : S_b;
    g1.N[i]   = g2.N[i]   = (i == 2) ? NA : NP;
  }
  g1.X[0] = xab; g1.X[1] = xpb; g1.X[2] = xpb;
  g2.X[0] = ha;  g2.X[1] = hp;  g2.X[2] = hp;

  // ---- prep ----
  warrange_k<<<dim3(8, 10), 256, 0, stream>>>(wa);
  cvt_bf16_k<<<(NP * DI / 4 + 255) / 256, 256, 0, stream>>>(xp, xpb, NP * DI / 4);
  cvt_bf16_k<<<(NA * DI / 4 + 255) / 256, 256, 0, stream>>>(xa, xab, NA * DI / 4);

  // ---- CSR build ----
  hipMemsetAsync(ws + 150400000, 0, 2000000, stream);
  hist3_k<<<dim3(gE, 3), 256, 0, stream>>>(ea);
  blocksum3_k<<<dim3(nbP, 3), 256, 0, stream>>>(sa);
  partials3_k<<<3, 256, 0, stream>>>(sa);
  scanwrite3_k<<<dim3(nbP, 3), 256, 0, stream>>>(sa);
  fill3_k<<<dim3(gE, 3), 256, 0, stream>>>(ea);

  // ---- layer 1 ----
  gather3_k<<<dim3(gG, 3), 256, 0, stream>>>(g1);
  fused_gemm_k<128, true, 3, true><<<gP, 256, 0, stream>>>(
      xpb, WF[3], S_w, WF[0], S_c, WF[1], b1rp, hp, NP);
  fused_gemm_k<128, true, 2, true><<<gA, 256, 0, stream>>>(
      xab, WF[4], S_b, WF[2], nullptr, nullptr, b1ra, ha, NA);

  // ---- layer 2 ----
  gather3_k<<<dim3(gG, 3), 256, 0, stream>>>(g2);
  fused_gemm_k<64, false, 3, false><<<gP, 256, 0, stream>>>(
      hp, WF[8], S_w, WF[5], S_c, WF[6], b2rp, outP, NP);
  fused_gemm_k<64, false, 2, false><<<gA, 256, 0, stream>>>(
      ha, WF[9], S_b, WF[7], nullptr, nullptr, b2ra, outA, NA);
}

// Round 5
// 443.515 us; speedup vs baseline: 14.4642x; 1.2215x over previous
//
#include <hip/hip_runtime.h>

// RGCN 2-layer hetero graph conv. fp32 I/O, bf16 MFMA compute.
// R5: atomic-free bucket fill. hist3's atomicAdd return value IS the edge's
// rank within its dst bucket (max is order-independent, so any permutation is
// valid); store it, and fill becomes a pure scatter (no cursor atomics, which
// were 173MB of coherence-point writeback = 118us). Also: merged cvt (2->1)
// and merged per-layer paper+author GEMMs (4->2 dispatches).

#define DI 128
#define NP 100000
#define NA 50000

typedef short s8v __attribute__((ext_vector_type(8)));
typedef float f32x4 __attribute__((ext_vector_type(4)));

__device__ __forceinline__ unsigned short bf16_rne(float f) {
  unsigned int fb = __float_as_uint(f);
  fb += 0x7FFFu + ((fb >> 16) & 1u);
  return (unsigned short)(fb >> 16);
}

// ---- fp32 -> bf16, both tables in one dispatch ----
__global__ __launch_bounds__(256) void cvt2_k(const float* __restrict__ Xp,
                                              unsigned short* __restrict__ Yp, int n4p,
                                              const float* __restrict__ Xa,
                                              unsigned short* __restrict__ Ya, int n4a) {
  int i = blockIdx.x * 256 + threadIdx.x;
  const float* X; unsigned short* Y;
  if (i < n4p) { X = Xp; Y = Yp; }
  else { i -= n4p; if (i >= n4a) return; X = Xa; Y = Ya; }
  float4 f = reinterpret_cast<const float4*>(X)[i];
  ushort4 o;
  o.x = bf16_rne(f.x); o.y = bf16_rne(f.y); o.z = bf16_rne(f.z); o.w = bf16_rne(f.w);
  reinterpret_cast<ushort4*>(Y)[i] = o;
}

// ==== CSR build (3 edge types in one dispatch via blockIdx.y) ====
struct E3Args {
  const int* src[3]; const int* dst[3];
  int* cnt[3]; int* erank[3]; const int* rs[3]; int* bkt[3];
  int E[3];
};

__global__ __launch_bounds__(256) void hist3_k(E3Args a) {
  int y = blockIdx.y;
  int e = blockIdx.x * 256 + threadIdx.x;
  if (e < a.E[y]) a.erank[y][e] = atomicAdd(&a.cnt[y][a.dst[y][e]], 1);
}

__global__ __launch_bounds__(256) void fill3_k(E3Args a) {
  int y = blockIdx.y;
  int e = blockIdx.x * 256 + threadIdx.x;
  if (e >= a.E[y]) return;
  int d = a.dst[y][e];
  a.bkt[y][a.rs[y][d] + a.erank[y][e]] = a.src[y][e];
}

struct S3Args {
  const int* cnt[3]; int* bsum[3]; int* rs[3];
  int n[3]; int nb[3];
};

__global__ __launch_bounds__(256) void blocksum3_k(S3Args a) {
  int y = blockIdx.y;
  int n = a.n[y];
  if (blockIdx.x * 1024 >= n) return;
  __shared__ int red[256];
  int t = threadIdx.x;
  int base = blockIdx.x * 1024 + t * 4;
  int s = 0;
  #pragma unroll
  for (int i = 0; i < 4; ++i) { int idx = base + i; if (idx < n) s += a.cnt[y][idx]; }
  red[t] = s; __syncthreads();
  #pragma unroll
  for (int o = 128; o > 0; o >>= 1) { if (t < o) red[t] += red[t + o]; __syncthreads(); }
  if (t == 0) a.bsum[y][blockIdx.x] = red[0];
}

__global__ __launch_bounds__(256) void partials3_k(S3Args a) {
  __shared__ int sm[256];
  int y = blockIdx.x;
  int nb = a.nb[y];
  int t = threadIdx.x;
  int v = (t < nb) ? a.bsum[y][t] : 0;
  sm[t] = v; __syncthreads();
  int acc = v;
  for (int o = 1; o < 256; o <<= 1) {
    int u = (t >= o) ? sm[t - o] : 0;
    __syncthreads();
    acc += u; sm[t] = acc;
    __syncthreads();
  }
  if (t < nb) a.bsum[y][t] = acc - v;  // exclusive
}

__global__ __launch_bounds__(256) void scanwrite3_k(S3Args a) {
  int y = blockIdx.y;
  int n = a.n[y];
  if (blockIdx.x * 1024 >= n) return;
  __shared__ int ts[256];
  int t = threadIdx.x;
  int base = blockIdx.x * 1024 + t * 4;
  int v[4]; int s = 0;
  #pragma unroll
  for (int i = 0; i < 4; ++i) { int idx = base + i; v[i] = (idx < n) ? a.cnt[y][idx] : 0; s += v[i]; }
  ts[t] = s; __syncthreads();
  int inc = s;
  for (int o = 1; o < 256; o <<= 1) {
    int u = (t >= o) ? ts[t - o] : 0;
    __syncthreads();
    inc += u; ts[t] = inc;
    __syncthreads();
  }
  int p = a.bsum[y][blockIdx.x] + inc - s;
  #pragma unroll
  for (int i = 0; i < 4; ++i) { int idx = base + i; if (idx < n) { a.rs[y][idx] = p; p += v[i]; } }
}

// ==== gather-max: 16 lanes/row (dwordx4), 4 rows/wave, 16 rows/block, 3-way y ====
struct G3Args {
  const int* cnt[3]; const int* rs[3]; const int* bkt[3];
  const unsigned short* X[3]; unsigned short* S[3];
  int N[3];
};

__global__ __launch_bounds__(256) void gather3_k(G3Args a) {
  const int y = blockIdx.y;
  const int lane = threadIdx.x & 63;
  const int wave = threadIdx.x >> 6;
  const int g = lane >> 4, lg = lane & 15;
  const int d = blockIdx.x * 16 + wave * 4 + g;
  if (d >= a.N[y]) return;

  unsigned short* So = a.S[y] + (size_t)d * DI + lg * 8;
  const int deg = a.cnt[y][d];
  if (deg == 0) {
    uint4 z; z.x = z.y = z.z = z.w = 0u;
    *reinterpret_cast<uint4*>(So) = z;
    return;
  }
  const int* bp = a.bkt[y] + a.rs[y][d];
  const unsigned short* X = a.X[y];

  float ml[4], mh[4];
  #pragma unroll
  for (int j = 0; j < 4; ++j) { ml[j] = -3.4e38f; mh[j] = -3.4e38f; }

  int s0 = bp[0];
  for (int e = 0; e < deg; e += 2) {
    int s1 = (e + 1 < deg) ? bp[e + 1] : s0;  // branchless tail: re-max same row
    int sn = (e + 2 < deg) ? bp[e + 2] : s0;
    uint4 r0 = *reinterpret_cast<const uint4*>(X + (size_t)s0 * DI + lg * 8);
    uint4 r1 = *reinterpret_cast<const uint4*>(X + (size_t)s1 * DI + lg * 8);
    unsigned int w0[4] = {r0.x, r0.y, r0.z, r0.w};
    unsigned int w1[4] = {r1.x, r1.y, r1.z, r1.w};
    #pragma unroll
    for (int j = 0; j < 4; ++j) {
      ml[j] = fmaxf(ml[j], __uint_as_float(w0[j] << 16));
      mh[j] = fmaxf(mh[j], __uint_as_float(w0[j] & 0xFFFF0000u));
      ml[j] = fmaxf(ml[j], __uint_as_float(w1[j] << 16));
      mh[j] = fmaxf(mh[j], __uint_as_float(w1[j] & 0xFFFF0000u));
    }
    s0 = sn;
  }
  uint4 o;
  o.x = (__float_as_uint(ml[0]) >> 16) | (__float_as_uint(mh[0]) & 0xFFFF0000u);
  o.y = (__float_as_uint(ml[1]) >> 16) | (__float_as_uint(mh[1]) & 0xFFFF0000u);
  o.z = (__float_as_uint(ml[2]) >> 16) | (__float_as_uint(mh[2]) & 0xFFFF0000u);
  o.w = (__float_as_uint(ml[3]) >> 16) | (__float_as_uint(mh[3]) & 0xFFFF0000u);
  *reinterpret_cast<uint4*>(So) = o;
}

// ---- weight rearrange (fp32 -> bf16 B-fragments): wf[((kc*CF+cf)*64+lane)*8+i]=W[k][c] ----
struct WArgs {
  const float* w[10];
  unsigned short* wf[10];
};
__global__ __launch_bounds__(256) void warrange_k(WArgs args) {
  int widx = blockIdx.y;
  int OUTi = (widx < 5) ? 128 : 64;
  int CF = OUTi / 16;
  int nt = 4 * CF * 64;
  int t = blockIdx.x * 256 + threadIdx.x;
  if (t >= nt) return;
  int lane = t & 63, tmp = t >> 6;
  int cf = tmp % CF, kc = tmp / CF;
  int k0 = kc * 32 + (lane >> 4) * 8;
  int c  = cf * 16 + (lane & 15);
  const float* w = args.w[widx];
  s8v v;
  #pragma unroll
  for (int i = 0; i < 8; ++i) v[i] = (short)bf16_rne(w[(k0 + i) * OUTi + c]);
  *(reinterpret_cast<s8v*>(args.wf[widx]) + t) = v;
}

// ==== fused GEMM pair: paper (3-src) blocks then author (2-src) blocks ====
// MFMA 16x16x32 bf16: A row=lane&15,k=(lane>>4)*8+i; B col=lane&15; D col=lane&15,row=(lane>>4)*4+reg
template<int CF>
__device__ __forceinline__ void mfma_accum(const unsigned short* __restrict__ A,
                                           const unsigned short* __restrict__ W,
                                           f32x4* acc, size_t arow, int lane, int half) {
  const s8v* a = reinterpret_cast<const s8v*>(A + arow * DI + half * 8);
  const s8v* w = reinterpret_cast<const s8v*>(W) + lane;
  #pragma unroll
  for (int kc = 0; kc < 4; ++kc) {
    s8v av = a[kc * 4];
    #pragma unroll
    for (int cf = 0; cf < CF; ++cf)
      acc[cf] = __builtin_amdgcn_mfma_f32_16x16x32_bf16(av, w[(kc * CF + cf) * 64], acc[cf], 0, 0, 0);
  }
}

struct GemmPairArgs {
  const unsigned short *A0[2], *W0[2], *A1[2], *W1[2], *A2, *W2;
  const float* bias[2];
  void* out[2];
  int N[2];
  int blocks0;
};

template<int OUT, bool RELU, bool OUT_BF16>
__global__ __launch_bounds__(256) void gemm_pair_k(GemmPairArgs g) {
  constexpr int CF = OUT / 16;
  const int p = (blockIdx.x >= (unsigned)g.blocks0) ? 1 : 0;
  const int brow = blockIdx.x - (p ? g.blocks0 : 0);
  const int N = g.N[p];
  const int lane = threadIdx.x & 63;
  const int wave = threadIdx.x >> 6;
  const int row0 = brow * 64 + wave * 16;
  if (row0 >= N) return;
  const int rl = lane & 15, half = lane >> 4;
  const size_t arow = (size_t)(row0 + rl);

  f32x4 acc[CF];
  #pragma unroll
  for (int i = 0; i < CF; ++i) acc[i] = f32x4{0.f, 0.f, 0.f, 0.f};

  mfma_accum<CF>(g.A0[p], g.W0[p], acc, arow, lane, half);
  mfma_accum<CF>(g.A1[p], g.W1[p], acc, arow, lane, half);
  if (!p) mfma_accum<CF>(g.A2, g.W2, acc, arow, lane, half);

  const float* bias = g.bias[p];
  #pragma unroll
  for (int cf = 0; cf < CF; ++cf) {
    float bv = bias[cf * 16 + rl];
    #pragma unroll
    for (int j = 0; j < 4; ++j) {
      int r = row0 + half * 4 + j;
      if (r >= N) continue;
      float v = acc[cf][j] + bv;
      if (RELU) v = v > 0.f ? v : 0.f;
      size_t idx = (size_t)r * OUT + cf * 16 + rl;
      if (OUT_BF16) ((unsigned short*)g.out[p])[idx] = bf16_rne(v);
      else          ((float*)g.out[p])[idx] = v;
    }
  }
}

extern "C" void kernel_launch(void* const* d_in, const int* in_sizes, int n_in,
                              void* d_out, int out_size, void* d_ws, size_t ws_size,
                              hipStream_t stream) {
  const float* xp = (const float*)d_in[0];
  const float* xa = (const float*)d_in[1];
  const int* wsrc = (const int*)d_in[2];
  const int* wdst = (const int*)d_in[3];
  const int* csrc = (const int*)d_in[4];
  const int* cdst = (const int*)d_in[5];
  const int* bsrc = (const int*)d_in[6];
  const int* bdst = (const int*)d_in[7];
  const int Ew = in_sizes[2], Ec = in_sizes[4], Eb = in_sizes[6];

  const float* w1w  = (const float*)d_in[8];
  const float* w1c  = (const float*)d_in[9];
  const float* w1wb = (const float*)d_in[10];
  const float* w1rp = (const float*)d_in[11];
  const float* b1rp = (const float*)d_in[12];
  const float* w1ra = (const float*)d_in[13];
  const float* b1ra = (const float*)d_in[14];
  const float* w2w  = (const float*)d_in[15];
  const float* w2c  = (const float*)d_in[16];
  const float* w2wb = (const float*)d_in[17];
  const float* w2rp = (const float*)d_in[18];
  const float* b2rp = (const float*)d_in[19];
  const float* w2ra = (const float*)d_in[20];
  const float* b2ra = (const float*)d_in[21];

  // ---- workspace layout (bytes) ----
  char* ws = (char*)d_ws;
  unsigned short* xpb = (unsigned short*)(ws + 0);           // 25,600,000
  unsigned short* xab = (unsigned short*)(ws + 25600000);    // 12,800,000
  unsigned short* hp  = (unsigned short*)(ws + 38400000);    // 25,600,000
  unsigned short* ha  = (unsigned short*)(ws + 64000000);    // 12,800,000
  unsigned short* S_w = (unsigned short*)(ws + 76800000);    // 25,600,000
  unsigned short* S_c = (unsigned short*)(ws + 102400000);   // 25,600,000
  unsigned short* S_b = (unsigned short*)(ws + 128000000);   // 12,800,000
  int* bkt_w = (int*)(ws + 140800000);                       // 3,200,000
  int* bkt_c = (int*)(ws + 144000000);                       // 3,200,000
  int* bkt_b = (int*)(ws + 147200000);                       // 3,200,000
  int* cnt_w = (int*)(ws + 150400000);                       // 400,000
  int* cnt_c = (int*)(ws + 150800000);                       // 400,000
  int* cnt_b = (int*)(ws + 151200000);                       // 200,000 (memset 1.0MB)
  int* rs_w  = (int*)(ws + 151400000);                       // 400,000
  int* rs_c  = (int*)(ws + 151800000);                       // 400,000
  int* rs_b  = (int*)(ws + 152200000);                       // 200,000
  int* bsum_w = (int*)(ws + 152400000);                      // 4,096
  int* bsum_c = (int*)(ws + 152404096);                      // 4,096
  int* bsum_b = (int*)(ws + 152408192);                      // 4,096
  unsigned short* wf = (unsigned short*)(ws + 152412288);    // 245,760
  int* erank_w = (int*)(ws + 152660000);                     // 3,200,000
  int* erank_c = (int*)(ws + 155860000);                     // 3,200,000
  int* erank_b = (int*)(ws + 159060000);                     // 3,200,000

  unsigned short* WF[10];
  size_t off = 0;
  for (int i = 0; i < 10; ++i) {
    WF[i] = wf + off;
    off += (i < 5) ? (size_t)128 * 128 : (size_t)128 * 64;
  }
  WArgs wa;
  const float* wsrcs[10] = {w1w, w1c, w1wb, w1rp, w1ra, w2w, w2c, w2wb, w2rp, w2ra};
  for (int i = 0; i < 10; ++i) { wa.w[i] = wsrcs[i]; wa.wf[i] = WF[i]; }

  float* outP = (float*)d_out;              // 100000 x 64 fp32
  float* outA = outP + (size_t)NP * 64;     // 50000 x 64 fp32

  const int gE  = (800000 + 255) / 256;
  const int nbP = (NP + 1023) / 1024, nbA = (NA + 1023) / 1024;  // 98, 49
  const int gP  = (NP + 63) / 64, gA = (NA + 63) / 64;           // 1563, 782
  const int gG  = (NP + 15) / 16;                                // 6250

  E3Args ea;
  ea.src[0] = wsrc; ea.dst[0] = wdst; ea.cnt[0] = cnt_w; ea.erank[0] = erank_w; ea.rs[0] = rs_w; ea.bkt[0] = bkt_w; ea.E[0] = Ew;
  ea.src[1] = csrc; ea.dst[1] = cdst; ea.cnt[1] = cnt_c; ea.erank[1] = erank_c; ea.rs[1] = rs_c; ea.bkt[1] = bkt_c; ea.E[1] = Ec;
  ea.src[2] = bsrc; ea.dst[2] = bdst; ea.cnt[2] = cnt_b; ea.erank[2] = erank_b; ea.rs[2] = rs_b; ea.bkt[2] = bkt_b; ea.E[2] = Eb;

  S3Args sa;
  sa.cnt[0] = cnt_w; sa.bsum[0] = bsum_w; sa.rs[0] = rs_w; sa.n[0] = NP; sa.nb[0] = nbP;
  sa.cnt[1] = cnt_c; sa.bsum[1] = bsum_c; sa.rs[1] = rs_c; sa.n[1] = NP; sa.nb[1] = nbP;
  sa.cnt[2] = cnt_b; sa.bsum[2] = bsum_b; sa.rs[2] = rs_b; sa.n[2] = NA; sa.nb[2] = nbA;

  G3Args g1, g2;
  for (int i = 0; i < 3; ++i) {
    g1.cnt[i] = g2.cnt[i] = (i == 0) ? cnt_w : (i == 1) ? cnt_c : cnt_b;
    g1.rs[i]  = g2.rs[i]  = (i == 0) ? rs_w  : (i == 1) ? rs_c  : rs_b;
    g1.bkt[i] = g2.bkt[i] = (i == 0) ? bkt_w : (i == 1) ? bkt_c : bkt_b;
    g1.S[i]   = g2.S[i]   = (i == 0) ? S_w   : (i == 1) ? S_c   : S_b;
    g1.N[i]   = g2.N[i]   = (i == 2) ? NA : NP;
  }
  g1.X[0] = xab; g1.X[1] = xpb; g1.X[2] = xpb;
  g2.X[0] = ha;  g2.X[1] = hp;  g2.X[2] = hp;

  GemmPairArgs p1, p2;
  // layer 1: paper = xpb@WF3 + S_w@WF0 + S_c@WF1 + b1rp -> hp; author = xab@WF4 + S_b@WF2 + b1ra -> ha
  p1.A0[0] = xpb; p1.W0[0] = WF[3]; p1.A1[0] = S_w; p1.W1[0] = WF[0]; p1.A2 = S_c; p1.W2 = WF[1];
  p1.bias[0] = b1rp; p1.out[0] = hp; p1.N[0] = NP;
  p1.A0[1] = xab; p1.W0[1] = WF[4]; p1.A1[1] = S_b; p1.W1[1] = WF[2];
  p1.bias[1] = b1ra; p1.out[1] = ha; p1.N[1] = NA;
  p1.blocks0 = gP;
  // layer 2: paper = hp@WF8 + S_w@WF5 + S_c@WF6 + b2rp -> outP; author = ha@WF9 + S_b@WF7 + b2ra -> outA
  p2.A0[0] = hp; p2.W0[0] = WF[8]; p2.A1[0] = S_w; p2.W1[0] = WF[5]; p2.A2 = S_c; p2.W2 = WF[6];
  p2.bias[0] = b2rp; p2.out[0] = outP; p2.N[0] = NP;
  p2.A0[1] = ha; p2.W0[1] = WF[9]; p2.A1[1] = S_b; p2.W1[1] = WF[7];
  p2.bias[1] = b2ra; p2.out[1] = outA; p2.N[1] = NA;
  p2.blocks0 = gP;

  const int n4p = NP * DI / 4, n4a = NA * DI / 4;

  // ---- prep ----
  warrange_k<<<dim3(8, 10), 256, 0, stream>>>(wa);
  cvt2_k<<<(n4p + n4a + 255) / 256, 256, 0, stream>>>(xp, xpb, n4p, xa, xab, n4a);

  // ---- CSR build ----
  hipMemsetAsync(ws + 150400000, 0, 1000000, stream);  // counts only
  hist3_k<<<dim3(gE, 3), 256, 0, stream>>>(ea);
  blocksum3_k<<<dim3(nbP, 3), 256, 0, stream>>>(sa);
  partials3_k<<<3, 256, 0, stream>>>(sa);
  scanwrite3_k<<<dim3(nbP, 3), 256, 0, stream>>>(sa);
  fill3_k<<<dim3(gE, 3), 256, 0, stream>>>(ea);

  // ---- layer 1 ----
  gather3_k<<<dim3(gG, 3), 256, 0, stream>>>(g1);
  gemm_pair_k<128, true, true><<<gP + gA, 256, 0, stream>>>(p1);

  // ---- layer 2 ----
  gather3_k<<<dim3(gG, 3), 256, 0, stream>>>(g2);
  gemm_pair_k<64, false, false><<<gP + gA, 256, 0, stream>>>(p2);
}

// Round 6
// 359.320 us; speedup vs baseline: 17.8534x; 1.2343x over previous
//
#include <hip/hip_runtime.h>

// RGCN 2-layer hetero graph conv. fp32 I/O, bf16 MFMA compute.
// R6: zero-global-atomic CSR build via 2-level MSD bucket sort.
//   S1: per-block LDS hist of dst>>8 -> bh[bin][blk]
//   scan bh (hierarchical, reused machinery) -> bhs
//   X1: scatter packed (dst&255)<<24|src into coarse buckets (LDS cursors)
//   P2: per coarse bucket: LDS hist+scan of low byte -> writes cnt[], rs[],
//       and dst-grouped bkt[] directly (replaces hist3/fill3/per-dst scan).
// Order within a dst bucket is arbitrary (LDS-atomic races) but max is
// order-independent and exact in bf16 -> output bit-deterministic.

#define DI 128
#define NP 100000
#define NA 50000
#define EPB 4096
#define MAXBIN 391

typedef short s8v __attribute__((ext_vector_type(8)));
typedef float f32x4 __attribute__((ext_vector_type(4)));

__device__ __forceinline__ unsigned short bf16_rne(float f) {
  unsigned int fb = __float_as_uint(f);
  fb += 0x7FFFu + ((fb >> 16) & 1u);
  return (unsigned short)(fb >> 16);
}

// ---- fp32 -> bf16, both tables in one dispatch ----
__global__ __launch_bounds__(256) void cvt2_k(const float* __restrict__ Xp,
                                              unsigned short* __restrict__ Yp, int n4p,
                                              const float* __restrict__ Xa,
                                              unsigned short* __restrict__ Ya, int n4a) {
  int i = blockIdx.x * 256 + threadIdx.x;
  const float* X; unsigned short* Y;
  if (i < n4p) { X = Xp; Y = Yp; }
  else { i -= n4p; if (i >= n4a) return; X = Xa; Y = Ya; }
  float4 f = reinterpret_cast<const float4*>(X)[i];
  ushort4 o;
  o.x = bf16_rne(f.x); o.y = bf16_rne(f.y); o.z = bf16_rne(f.z); o.w = bf16_rne(f.w);
  reinterpret_cast<ushort4*>(Y)[i] = o;
}

// ==== radix CSR build (3 edge types via blockIdx.y) ====
struct R3Args {
  const int* src[3]; const int* dst[3];
  int* bh[3]; int* bhs[3];
  unsigned int* tmp[3];
  int* bkt[3]; int* cnt[3]; int* rs[3];
  int E[3]; int N[3]; int nbin[3]; int NB[3];
};

__global__ __launch_bounds__(256) void radix_s1_k(R3Args a) {
  int y = blockIdx.y, blk = blockIdx.x;
  int NB = a.NB[y];
  if (blk >= NB) return;
  __shared__ int hist[MAXBIN];
  int nbin = a.nbin[y];
  for (int i = threadIdx.x; i < nbin; i += 256) hist[i] = 0;
  __syncthreads();
  int e0 = blk * EPB, e1 = min(e0 + EPB, a.E[y]);
  const int* dst = a.dst[y];
  for (int e = e0 + threadIdx.x; e < e1; e += 256)
    atomicAdd(&hist[dst[e] >> 8], 1);
  __syncthreads();
  int* bh = a.bh[y];
  for (int i = threadIdx.x; i < nbin; i += 256) bh[i * NB + blk] = hist[i];
}

__global__ __launch_bounds__(256) void radix_x1_k(R3Args a) {
  int y = blockIdx.y, blk = blockIdx.x;
  int NB = a.NB[y];
  if (blk >= NB) return;
  __shared__ int cur[MAXBIN];
  int nbin = a.nbin[y];
  const int* bhs = a.bhs[y];
  for (int i = threadIdx.x; i < nbin; i += 256) cur[i] = bhs[i * NB + blk];
  __syncthreads();
  int e0 = blk * EPB, e1 = min(e0 + EPB, a.E[y]);
  const int* dst = a.dst[y];
  const int* src = a.src[y];
  unsigned int* tmp = a.tmp[y];
  for (int e = e0 + threadIdx.x; e < e1; e += 256) {
    int d = dst[e];
    int pos = atomicAdd(&cur[d >> 8], 1);
    tmp[pos] = ((unsigned int)(d & 255) << 24) | (unsigned int)src[e];
  }
}

__global__ __launch_bounds__(256) void radix_p2_k(R3Args a) {
  int y = blockIdx.y, bin = blockIdx.x;
  if (bin >= a.nbin[y]) return;
  __shared__ int hist[256], scn[256], cursor[256];
  int t = threadIdx.x;
  hist[t] = 0;
  __syncthreads();
  const int* bhs = a.bhs[y];
  int NB = a.NB[y];
  int base = bhs[bin * NB];
  int end  = (bin + 1 < a.nbin[y]) ? bhs[(bin + 1) * NB] : a.E[y];
  const unsigned int* tmp = a.tmp[y];
  for (int i = base + t; i < end; i += 256)
    atomicAdd(&hist[tmp[i] >> 24], 1);
  __syncthreads();
  int v = hist[t];
  scn[t] = v; __syncthreads();
  int acc = v;
  for (int o = 1; o < 256; o <<= 1) {
    int u = (t >= o) ? scn[t - o] : 0;
    __syncthreads();
    acc += u; scn[t] = acc;
    __syncthreads();
  }
  int ex = acc - v;          // exclusive low-byte prefix
  cursor[t] = ex;
  int d = bin * 256 + t;
  if (d < a.N[y]) { a.cnt[y][d] = v; a.rs[y][d] = base + ex; }
  __syncthreads();
  int* bkt = a.bkt[y];
  for (int i = base + t; i < end; i += 256) {
    unsigned int p = tmp[i];
    int pos = atomicAdd(&cursor[p >> 24], 1);
    bkt[base + pos] = (int)(p & 0xFFFFFFu);
  }
}

// ==== hierarchical exclusive scan (reused for bh -> bhs) ====
struct S3Args {
  const int* cnt[3]; int* bsum[3]; int* rs[3];
  int n[3]; int nb[3];
};

__global__ __launch_bounds__(256) void blocksum3_k(S3Args a) {
  int y = blockIdx.y;
  int n = a.n[y];
  if (blockIdx.x * 1024 >= n) return;
  __shared__ int red[256];
  int t = threadIdx.x;
  int base = blockIdx.x * 1024 + t * 4;
  int s = 0;
  #pragma unroll
  for (int i = 0; i < 4; ++i) { int idx = base + i; if (idx < n) s += a.cnt[y][idx]; }
  red[t] = s; __syncthreads();
  #pragma unroll
  for (int o = 128; o > 0; o >>= 1) { if (t < o) red[t] += red[t + o]; __syncthreads(); }
  if (t == 0) a.bsum[y][blockIdx.x] = red[0];
}

__global__ __launch_bounds__(256) void partials3_k(S3Args a) {
  __shared__ int sm[256];
  int y = blockIdx.x;
  int nb = a.nb[y];
  int t = threadIdx.x;
  int v = (t < nb) ? a.bsum[y][t] : 0;
  sm[t] = v; __syncthreads();
  int acc = v;
  for (int o = 1; o < 256; o <<= 1) {
    int u = (t >= o) ? sm[t - o] : 0;
    __syncthreads();
    acc += u; sm[t] = acc;
    __syncthreads();
  }
  if (t < nb) a.bsum[y][t] = acc - v;  // exclusive
}

__global__ __launch_bounds__(256) void scanwrite3_k(S3Args a) {
  int y = blockIdx.y;
  int n = a.n[y];
  if (blockIdx.x * 1024 >= n) return;
  __shared__ int ts[256];
  int t = threadIdx.x;
  int base = blockIdx.x * 1024 + t * 4;
  int v[4]; int s = 0;
  #pragma unroll
  for (int i = 0; i < 4; ++i) { int idx = base + i; v[i] = (idx < n) ? a.cnt[y][idx] : 0; s += v[i]; }
  ts[t] = s; __syncthreads();
  int inc = s;
  for (int o = 1; o < 256; o <<= 1) {
    int u = (t >= o) ? ts[t - o] : 0;
    __syncthreads();
    inc += u; ts[t] = inc;
    __syncthreads();
  }
  int p = a.bsum[y][blockIdx.x] + inc - s;
  #pragma unroll
  for (int i = 0; i < 4; ++i) { int idx = base + i; if (idx < n) { a.rs[y][idx] = p; p += v[i]; } }
}

// ==== gather-max: 16 lanes/row (dwordx4), 4 rows/wave, 16 rows/block, 3-way y ====
struct G3Args {
  const int* cnt[3]; const int* rs[3]; const int* bkt[3];
  const unsigned short* X[3]; unsigned short* S[3];
  int N[3];
};

__global__ __launch_bounds__(256) void gather3_k(G3Args a) {
  const int y = blockIdx.y;
  const int lane = threadIdx.x & 63;
  const int wave = threadIdx.x >> 6;
  const int g = lane >> 4, lg = lane & 15;
  const int d = blockIdx.x * 16 + wave * 4 + g;
  if (d >= a.N[y]) return;

  unsigned short* So = a.S[y] + (size_t)d * DI + lg * 8;
  const int deg = a.cnt[y][d];
  if (deg == 0) {
    uint4 z; z.x = z.y = z.z = z.w = 0u;
    *reinterpret_cast<uint4*>(So) = z;
    return;
  }
  const int* bp = a.bkt[y] + a.rs[y][d];
  const unsigned short* X = a.X[y];

  float ml[4], mh[4];
  #pragma unroll
  for (int j = 0; j < 4; ++j) { ml[j] = -3.4e38f; mh[j] = -3.4e38f; }

  int s0 = bp[0];
  for (int e = 0; e < deg; e += 2) {
    int s1 = (e + 1 < deg) ? bp[e + 1] : s0;  // branchless tail: re-max same row
    int sn = (e + 2 < deg) ? bp[e + 2] : s0;
    uint4 r0 = *reinterpret_cast<const uint4*>(X + (size_t)s0 * DI + lg * 8);
    uint4 r1 = *reinterpret_cast<const uint4*>(X + (size_t)s1 * DI + lg * 8);
    unsigned int w0[4] = {r0.x, r0.y, r0.z, r0.w};
    unsigned int w1[4] = {r1.x, r1.y, r1.z, r1.w};
    #pragma unroll
    for (int j = 0; j < 4; ++j) {
      ml[j] = fmaxf(ml[j], __uint_as_float(w0[j] << 16));
      mh[j] = fmaxf(mh[j], __uint_as_float(w0[j] & 0xFFFF0000u));
      ml[j] = fmaxf(ml[j], __uint_as_float(w1[j] << 16));
      mh[j] = fmaxf(mh[j], __uint_as_float(w1[j] & 0xFFFF0000u));
    }
    s0 = sn;
  }
  uint4 o;
  o.x = (__float_as_uint(ml[0]) >> 16) | (__float_as_uint(mh[0]) & 0xFFFF0000u);
  o.y = (__float_as_uint(ml[1]) >> 16) | (__float_as_uint(mh[1]) & 0xFFFF0000u);
  o.z = (__float_as_uint(ml[2]) >> 16) | (__float_as_uint(mh[2]) & 0xFFFF0000u);
  o.w = (__float_as_uint(ml[3]) >> 16) | (__float_as_uint(mh[3]) & 0xFFFF0000u);
  *reinterpret_cast<uint4*>(So) = o;
}

// ---- weight rearrange (fp32 -> bf16 B-fragments): wf[((kc*CF+cf)*64+lane)*8+i]=W[k][c] ----
struct WArgs {
  const float* w[10];
  unsigned short* wf[10];
};
__global__ __launch_bounds__(256) void warrange_k(WArgs args) {
  int widx = blockIdx.y;
  int OUTi = (widx < 5) ? 128 : 64;
  int CF = OUTi / 16;
  int nt = 4 * CF * 64;
  int t = blockIdx.x * 256 + threadIdx.x;
  if (t >= nt) return;
  int lane = t & 63, tmp = t >> 6;
  int cf = tmp % CF, kc = tmp / CF;
  int k0 = kc * 32 + (lane >> 4) * 8;
  int c  = cf * 16 + (lane & 15);
  const float* w = args.w[widx];
  s8v v;
  #pragma unroll
  for (int i = 0; i < 8; ++i) v[i] = (short)bf16_rne(w[(k0 + i) * OUTi + c]);
  *(reinterpret_cast<s8v*>(args.wf[widx]) + t) = v;
}

// ==== fused GEMM pair: paper (3-src) blocks then author (2-src) blocks ====
// MFMA 16x16x32 bf16: A row=lane&15,k=(lane>>4)*8+i; B col=lane&15; D col=lane&15,row=(lane>>4)*4+reg
template<int CF>
__device__ __forceinline__ void mfma_accum(const unsigned short* __restrict__ A,
                                           const unsigned short* __restrict__ W,
                                           f32x4* acc, size_t arow, int lane, int half) {
  const s8v* a = reinterpret_cast<const s8v*>(A + arow * DI + half * 8);
  const s8v* w = reinterpret_cast<const s8v*>(W) + lane;
  #pragma unroll
  for (int kc = 0; kc < 4; ++kc) {
    s8v av = a[kc * 4];
    #pragma unroll
    for (int cf = 0; cf < CF; ++cf)
      acc[cf] = __builtin_amdgcn_mfma_f32_16x16x32_bf16(av, w[(kc * CF + cf) * 64], acc[cf], 0, 0, 0);
  }
}

struct GemmPairArgs {
  const unsigned short *A0[2], *W0[2], *A1[2], *W1[2], *A2, *W2;
  const float* bias[2];
  void* out[2];
  int N[2];
  int blocks0;
};

template<int OUT, bool RELU, bool OUT_BF16>
__global__ __launch_bounds__(256) void gemm_pair_k(GemmPairArgs g) {
  constexpr int CF = OUT / 16;
  const int p = (blockIdx.x >= (unsigned)g.blocks0) ? 1 : 0;
  const int brow = blockIdx.x - (p ? g.blocks0 : 0);
  const int N = g.N[p];
  const int lane = threadIdx.x & 63;
  const int wave = threadIdx.x >> 6;
  const int row0 = brow * 64 + wave * 16;
  if (row0 >= N) return;
  const int rl = lane & 15, half = lane >> 4;
  const size_t arow = (size_t)(row0 + rl);

  f32x4 acc[CF];
  #pragma unroll
  for (int i = 0; i < CF; ++i) acc[i] = f32x4{0.f, 0.f, 0.f, 0.f};

  mfma_accum<CF>(g.A0[p], g.W0[p], acc, arow, lane, half);
  mfma_accum<CF>(g.A1[p], g.W1[p], acc, arow, lane, half);
  if (!p) mfma_accum<CF>(g.A2, g.W2, acc, arow, lane, half);

  const float* bias = g.bias[p];
  #pragma unroll
  for (int cf = 0; cf < CF; ++cf) {
    float bv = bias[cf * 16 + rl];
    #pragma unroll
    for (int j = 0; j < 4; ++j) {
      int r = row0 + half * 4 + j;
      if (r >= N) continue;
      float v = acc[cf][j] + bv;
      if (RELU) v = v > 0.f ? v : 0.f;
      size_t idx = (size_t)r * OUT + cf * 16 + rl;
      if (OUT_BF16) ((unsigned short*)g.out[p])[idx] = bf16_rne(v);
      else          ((float*)g.out[p])[idx] = v;
    }
  }
}

extern "C" void kernel_launch(void* const* d_in, const int* in_sizes, int n_in,
                              void* d_out, int out_size, void* d_ws, size_t ws_size,
                              hipStream_t stream) {
  const float* xp = (const float*)d_in[0];
  const float* xa = (const float*)d_in[1];
  const int* wsrc = (const int*)d_in[2];
  const int* wdst = (const int*)d_in[3];
  const int* csrc = (const int*)d_in[4];
  const int* cdst = (const int*)d_in[5];
  const int* bsrc = (const int*)d_in[6];
  const int* bdst = (const int*)d_in[7];
  const int Ew = in_sizes[2], Ec = in_sizes[4], Eb = in_sizes[6];

  const float* w1w  = (const float*)d_in[8];
  const float* w1c  = (const float*)d_in[9];
  const float* w1wb = (const float*)d_in[10];
  const float* w1rp = (const float*)d_in[11];
  const float* b1rp = (const float*)d_in[12];
  const float* w1ra = (const float*)d_in[13];
  const float* b1ra = (const float*)d_in[14];
  const float* w2w  = (const float*)d_in[15];
  const float* w2c  = (const float*)d_in[16];
  const float* w2wb = (const float*)d_in[17];
  const float* w2rp = (const float*)d_in[18];
  const float* b2rp = (const float*)d_in[19];
  const float* w2ra = (const float*)d_in[20];
  const float* b2ra = (const float*)d_in[21];

  // ---- workspace layout (bytes); peak use 162.26MB (same as R5) ----
  char* ws = (char*)d_ws;
  unsigned short* xpb = (unsigned short*)(ws + 0);           // 25,600,000
  unsigned short* xab = (unsigned short*)(ws + 25600000);    // 12,800,000
  unsigned short* hp  = (unsigned short*)(ws + 38400000);    // 25,600,000
  unsigned short* ha  = (unsigned short*)(ws + 64000000);    // 12,800,000
  unsigned short* S_w = (unsigned short*)(ws + 76800000);    // 25,600,000
  unsigned short* S_c = (unsigned short*)(ws + 102400000);   // 25,600,000
  unsigned short* S_b = (unsigned short*)(ws + 128000000);   // 12,800,000
  int* bkt_w = (int*)(ws + 140800000);                       // 3,200,000
  int* bkt_c = (int*)(ws + 144000000);                       // 3,200,000
  int* bkt_b = (int*)(ws + 147200000);                       // 3,200,000
  int* cnt_w = (int*)(ws + 150400000);                       // 400,000
  int* cnt_c = (int*)(ws + 150800000);                       // 400,000
  int* cnt_b = (int*)(ws + 151200000);                       // 200,000
  int* rs_w  = (int*)(ws + 151400000);                       // 400,000
  int* rs_c  = (int*)(ws + 151800000);                       // 400,000
  int* rs_b  = (int*)(ws + 152200000);                       // 200,000
  int* bsum_w = (int*)(ws + 152400000);                      // 4,096
  int* bsum_c = (int*)(ws + 152404096);                      // 4,096
  int* bsum_b = (int*)(ws + 152408192);                      // 4,096
  unsigned short* wf = (unsigned short*)(ws + 152412288);    // 245,760
  unsigned int* tmp_w = (unsigned int*)(ws + 152660000);     // 3,200,000
  unsigned int* tmp_c = (unsigned int*)(ws + 155860000);     // 3,200,000
  unsigned int* tmp_b = (unsigned int*)(ws + 159060000);     // 3,200,000
  // bh/bhs live in S_w's region (dead until gather overwrites it after P2)
  int* bh_w  = (int*)(ws + 76800000);                        // 306,544
  int* bh_c  = (int*)(ws + 77110000);                        // 306,544
  int* bh_b  = (int*)(ws + 77420000);                        // 153,664
  int* bhs_w = (int*)(ws + 77580000);                        // 306,544
  int* bhs_c = (int*)(ws + 77890000);                        // 306,544
  int* bhs_b = (int*)(ws + 78200000);                        // 153,664

  unsigned short* WF[10];
  size_t off = 0;
  for (int i = 0; i < 10; ++i) {
    WF[i] = wf + off;
    off += (i < 5) ? (size_t)128 * 128 : (size_t)128 * 64;
  }
  WArgs wa;
  const float* wsrcs[10] = {w1w, w1c, w1wb, w1rp, w1ra, w2w, w2c, w2wb, w2rp, w2ra};
  for (int i = 0; i < 10; ++i) { wa.w[i] = wsrcs[i]; wa.wf[i] = WF[i]; }

  float* outP = (float*)d_out;              // 100000 x 64 fp32
  float* outA = outP + (size_t)NP * 64;     // 50000 x 64 fp32

  const int gP = (NP + 63) / 64, gA = (NA + 63) / 64;  // 1563, 782
  const int gG = (NP + 15) / 16;                       // 6250

  // ---- radix CSR args ----
  R3Args ra;
  ra.src[0] = wsrc; ra.dst[0] = wdst; ra.E[0] = Ew; ra.N[0] = NP;
  ra.src[1] = csrc; ra.dst[1] = cdst; ra.E[1] = Ec; ra.N[1] = NP;
  ra.src[2] = bsrc; ra.dst[2] = bdst; ra.E[2] = Eb; ra.N[2] = NA;
  ra.bh[0] = bh_w; ra.bh[1] = bh_c; ra.bh[2] = bh_b;
  ra.bhs[0] = bhs_w; ra.bhs[1] = bhs_c; ra.bhs[2] = bhs_b;
  ra.tmp[0] = tmp_w; ra.tmp[1] = tmp_c; ra.tmp[2] = tmp_b;
  ra.bkt[0] = bkt_w; ra.bkt[1] = bkt_c; ra.bkt[2] = bkt_b;
  ra.cnt[0] = cnt_w; ra.cnt[1] = cnt_c; ra.cnt[2] = cnt_b;
  ra.rs[0] = rs_w; ra.rs[1] = rs_c; ra.rs[2] = rs_b;
  int gSX = 0, gSC = 0, maxbin = 0;
  for (int y = 0; y < 3; ++y) {
    ra.nbin[y] = (ra.N[y] + 255) >> 8;                 // 391, 391, 196
    ra.NB[y] = (ra.E[y] + EPB - 1) / EPB;              // 196 each
    if (ra.NB[y] > gSX) gSX = ra.NB[y];
    if (ra.nbin[y] > maxbin) maxbin = ra.nbin[y];
  }
  S3Args sa;
  sa.bsum[0] = bsum_w; sa.bsum[1] = bsum_c; sa.bsum[2] = bsum_b;
  for (int y = 0; y < 3; ++y) {
    sa.cnt[y] = ra.bh[y]; sa.rs[y] = ra.bhs[y];
    sa.n[y] = ra.nbin[y] * ra.NB[y];                   // 76636, 76636, 38416
    sa.nb[y] = (sa.n[y] + 1023) / 1024;                // 75, 75, 38
    if (sa.nb[y] > gSC) gSC = sa.nb[y];
  }

  G3Args g1, g2;
  for (int i = 0; i < 3; ++i) {
    g1.cnt[i] = g2.cnt[i] = (i == 0) ? cnt_w : (i == 1) ? cnt_c : cnt_b;
    g1.rs[i]  = g2.rs[i]  = (i == 0) ? rs_w  : (i == 1) ? rs_c  : rs_b;
    g1.bkt[i] = g2.bkt[i] = (i == 0) ? bkt_w : (i == 1) ? bkt_c : bkt_b;
    g1.S[i]   = g2.S[i]   = (i == 0) ? S_w   : (i == 1) ? S_c   : S_b;
    g1.N[i]   = g2.N[i]   = (i == 2) ? NA : NP;
  }
  g1.X[0] = xab; g1.X[1] = xpb; g1.X[2] = xpb;
  g2.X[0] = ha;  g2.X[1] = hp;  g2.X[2] = hp;

  GemmPairArgs p1, p2;
  p1.A0[0] = xpb; p1.W0[0] = WF[3]; p1.A1[0] = S_w; p1.W1[0] = WF[0]; p1.A2 = S_c; p1.W2 = WF[1];
  p1.bias[0] = b1rp; p1.out[0] = hp; p1.N[0] = NP;
  p1.A0[1] = xab; p1.W0[1] = WF[4]; p1.A1[1] = S_b; p1.W1[1] = WF[2];
  p1.bias[1] = b1ra; p1.out[1] = ha; p1.N[1] = NA;
  p1.blocks0 = gP;
  p2.A0[0] = hp; p2.W0[0] = WF[8]; p2.A1[0] = S_w; p2.W1[0] = WF[5]; p2.A2 = S_c; p2.W2 = WF[6];
  p2.bias[0] = b2rp; p2.out[0] = outP; p2.N[0] = NP;
  p2.A0[1] = ha; p2.W0[1] = WF[9]; p2.A1[1] = S_b; p2.W1[1] = WF[7];
  p2.bias[1] = b2ra; p2.out[1] = outA; p2.N[1] = NA;
  p2.blocks0 = gP;

  const int n4p = NP * DI / 4, n4a = NA * DI / 4;

  // ---- prep ----
  warrange_k<<<dim3(8, 10), 256, 0, stream>>>(wa);
  cvt2_k<<<(n4p + n4a + 255) / 256, 256, 0, stream>>>(xp, xpb, n4p, xa, xab, n4a);

  // ---- CSR build (no global atomics, no memsets) ----
  radix_s1_k<<<dim3(gSX, 3), 256, 0, stream>>>(ra);
  blocksum3_k<<<dim3(gSC, 3), 256, 0, stream>>>(sa);
  partials3_k<<<3, 256, 0, stream>>>(sa);
  scanwrite3_k<<<dim3(gSC, 3), 256, 0, stream>>>(sa);
  radix_x1_k<<<dim3(gSX, 3), 256, 0, stream>>>(ra);
  radix_p2_k<<<dim3(maxbin, 3), 256, 0, stream>>>(ra);

  // ---- layer 1 ----
  gather3_k<<<dim3(gG, 3), 256, 0, stream>>>(g1);
  gemm_pair_k<128, true, true><<<gP + gA, 256, 0, stream>>>(p1);

  // ---- layer 2 ----
  gather3_k<<<dim3(gG, 3), 256, 0, stream>>>(g2);
  gemm_pair_k<64, false, false><<<gP + gA, 256, 0, stream>>>(p2);
}